// Round 6
// baseline (683.327 us; speedup 1.0000x reference)
//
#include <hip/hip_runtime.h>
#include <hip/hip_bf16.h>
#include <cstddef>

#define NXX 512
#define NUU 128
#define NDD 64
#define BB  256
#define TT  256
#define CL  8
#define NC  32
#define BS  (BB * NXX)     // one slab in elements (256*512)
#define MS  (NXX * NXX)    // one 512x512 matrix in elements
#define LDK 32             // LDS row stride (bf16) for 128x32 staging tiles

typedef __attribute__((ext_vector_type(8))) short short8;
typedef __attribute__((ext_vector_type(8))) unsigned short ushort8;
typedef __attribute__((ext_vector_type(4))) unsigned short ushort4v;
typedef __attribute__((ext_vector_type(4))) float f32x4;

__device__ __forceinline__ unsigned short f2bf(float f) {
    union { float f; unsigned u; } v; v.f = f;
    unsigned r = v.u + 0x7FFFu + ((v.u >> 16) & 1u);   // RNE
    return (unsigned short)(r >> 16);
}
__device__ __forceinline__ float bf2f(unsigned short h) {
    union { unsigned u; float f; } v; v.u = ((unsigned)h) << 16;
    return v.f;
}

// ---------------------------------------------------------------------------
// 2-phase double-buffered 128x128-tile GEMM machinery (mulN / hs / xcorr).
// ---------------------------------------------------------------------------
enum StageKind { SK_BF16_NAT, SK_BF16_TRANS };

__device__ __forceinline__ void stage_nat(const unsigned short* s, int ld, int r0,
                                          int k0, unsigned short (*S)[LDK])
{
    const int tid = threadIdx.x;
    const int wave = tid >> 6, lane = tid & 63;
#pragma unroll
    for (int i = 0; i < 2; ++i) {
        int rb = wave * 16 + i * 64;      // wave-uniform row base
        int r  = rb + (lane >> 2);
        int c  = (lane & 3) << 3;
        const unsigned short* g = s + (size_t)(r0 + r) * ld + k0 + c;
        __builtin_amdgcn_global_load_lds(
            (const __attribute__((address_space(1))) void*)g,
            (__attribute__((address_space(3))) void*)&S[rb][0],
            16, 0, 0);
    }
}
__device__ __forceinline__ ushort8 ldT(const unsigned short* s, int ld, int r0,
                                       int k0, int i)
{
    int idx = threadIdx.x + i * 256;
    int m   = idx >> 4;                   // 0..31 contraction row
    int c   = (idx & 15) << 3;            // 0..120 output col
    return *(const ushort8*)(s + (size_t)(k0 + m) * ld + r0 + c);
}
__device__ __forceinline__ void wrT(ushort8 v, int i, unsigned short (*S)[LDK])
{
    int idx = threadIdx.x + i * 256;
    int m   = idx >> 4;
    int c   = (idx & 15) << 3;
#pragma unroll
    for (int j = 0; j < 8; ++j) S[c + j][m] = v[j];
}

template<StageKind AK, StageKind BK>
__device__ __forceinline__ void gemm2_mainloop(
    f32x4 (&acc)[4][4],
    const void* A, int lda, const void* B, int ldb,
    int K, int row0, int n0,
    unsigned short (*As)[128][LDK], unsigned short (*Bs)[128][LDK])
{
    const int tid  = threadIdx.x;
    const int lane = tid & 63;
    const int wave = tid >> 6;
    const int wm   = (wave >> 1) * 64;
    const int wn   = (wave & 1) * 64;
    const int l16  = lane & 15;
    const int quad = lane >> 4;
    const unsigned short* Ap = (const unsigned short*)A;
    const unsigned short* Bp = (const unsigned short*)B;
    const int NT = K >> 5;

    if constexpr (AK == SK_BF16_NAT) stage_nat(Ap, lda, row0, 0, As[0]);
    else { wrT(ldT(Ap, lda, row0, 0, 0), 0, As[0]); wrT(ldT(Ap, lda, row0, 0, 1), 1, As[0]); }
    if constexpr (BK == SK_BF16_NAT) stage_nat(Bp, ldb, n0, 0, Bs[0]);
    else { wrT(ldT(Bp, ldb, n0, 0, 0), 0, Bs[0]); wrT(ldT(Bp, ldb, n0, 0, 1), 1, Bs[0]); }
    __syncthreads();

    for (int t = 0; t < NT; ++t) {
        const int cur = t & 1, nxt = cur ^ 1;
        const int k1  = (t + 1) << 5;
        ushort8 ta0, ta1, tb0, tb1;
        if (t + 1 < NT) {
            if constexpr (AK == SK_BF16_NAT) stage_nat(Ap, lda, row0, k1, As[nxt]);
            else { ta0 = ldT(Ap, lda, row0, k1, 0); ta1 = ldT(Ap, lda, row0, k1, 1); }
            if constexpr (BK == SK_BF16_NAT) stage_nat(Bp, ldb, n0, k1, Bs[nxt]);
            else { tb0 = ldT(Bp, ldb, n0, k1, 0); tb1 = ldT(Bp, ldb, n0, k1, 1); }
        }
        short8 af[4], bfr[4];
#pragma unroll
        for (int f = 0; f < 4; ++f)
            af[f] = *(const short8*)&As[cur][wm + f * 16 + l16][quad * 8];
#pragma unroll
        for (int f = 0; f < 4; ++f)
            bfr[f] = *(const short8*)&Bs[cur][wn + f * 16 + l16][quad * 8];
#pragma unroll
        for (int fm = 0; fm < 4; ++fm)
#pragma unroll
            for (int fn = 0; fn < 4; ++fn)
                acc[fm][fn] = __builtin_amdgcn_mfma_f32_16x16x32_bf16(
                    af[fm], bfr[fn], acc[fm][fn], 0, 0, 0);
        if (t + 1 < NT) {
            if constexpr (AK == SK_BF16_TRANS) { wrT(ta0, 0, As[nxt]); wrT(ta1, 1, As[nxt]); }
            if constexpr (BK == SK_BF16_TRANS) { wrT(tb0, 0, Bs[nxt]); wrT(tb1, 1, Bs[nxt]); }
        }
        __syncthreads();
    }
}

// ---------------------------------------------------------------------------
// T1[n][k] = (1 - 0.1*sigmoid(Asc[n][k])) * softmax(Aw[n,:])[k]  (bf16 T-layout)
// ---------------------------------------------------------------------------
__global__ __launch_bounds__(256) void k_weff(
    const float* __restrict__ Aw, const float* __restrict__ Asc,
    unsigned short* __restrict__ T1)
{
    const int n   = blockIdx.x;
    const int tid = threadIdx.x;
    const int lane = tid & 63, wave = tid >> 6;
    float v0 = Aw[(size_t)n * NXX + tid];
    float v1 = Aw[(size_t)n * NXX + 256 + tid];
    __shared__ float sred[4];
    float m = fmaxf(v0, v1);
#pragma unroll
    for (int off = 32; off; off >>= 1) m = fmaxf(m, __shfl_down(m, off));
    if (lane == 0) sred[wave] = m;
    __syncthreads();
    if (tid == 0) sred[0] = fmaxf(fmaxf(sred[0], sred[1]), fmaxf(sred[2], sred[3]));
    __syncthreads();
    const float mm = sred[0];
    __syncthreads();
    float e0 = expf(v0 - mm), e1 = expf(v1 - mm);
    float s = e0 + e1;
#pragma unroll
    for (int off = 32; off; off >>= 1) s += __shfl_down(s, off);
    if (lane == 0) sred[wave] = s;
    __syncthreads();
    if (tid == 0) sred[0] = sred[0] + sred[1] + sred[2] + sred[3];
    __syncthreads();
    const float inv = 1.0f / sred[0];
    float sc0 = 1.0f - 0.1f * (1.0f / (1.0f + expf(-Asc[(size_t)n * NXX + tid])));
    float sc1 = 1.0f - 0.1f * (1.0f / (1.0f + expf(-Asc[(size_t)n * NXX + 256 + tid])));
    unsigned short* out = T1 + (size_t)n * NXX;
    out[tid]       = f2bf(sc0 * e0 * inv);
    out[tid + 256] = f2bf(sc1 * e1 * inv);
}

// ---------------------------------------------------------------------------
// elementwise f32->bf16 prep: Bw (512x128), Ew (512x64), x (256x512 -> G slab 0)
// ---------------------------------------------------------------------------
__global__ __launch_bounds__(256) void k_prep(
    const float* __restrict__ Bw, const float* __restrict__ Ew,
    const float* __restrict__ x,
    unsigned short* __restrict__ Bwb, unsigned short* __restrict__ Ewb,
    unsigned short* __restrict__ G0)
{
    int i = (blockIdx.x * 256 + threadIdx.x) * 4;
    const float* src; unsigned short* dst; int k;
    if (i < 65536)       { src = Bw; dst = Bwb; k = i; }
    else if (i < 98304)  { src = Ew; dst = Ewb; k = i - 65536; }
    else                 { src = x;  dst = G0;  k = i - 98304; }
    float4 v = *(const float4*)(src + k);
    ushort4v h = { f2bf(v.x), f2bf(v.y), f2bf(v.z), f2bf(v.w) };
    *(ushort4v*)(dst + k) = h;
}

// ---------------------------------------------------------------------------
// Batched power products in T-space: slot ds[z] = slot ns[z] (NAT) * ts[z] (TRANS)
// ---------------------------------------------------------------------------
__global__ __launch_bounds__(256) void k_mulN(unsigned short* __restrict__ powb,
                                              int4 ns, int4 ts, int4 ds)
{
    const int z = blockIdx.z;
    const int an = (z == 0) ? ns.x : (z == 1) ? ns.y : (z == 2) ? ns.z : ns.w;
    const int at = (z == 0) ? ts.x : (z == 1) ? ts.y : (z == 2) ? ts.z : ts.w;
    const int ad = (z == 0) ? ds.x : (z == 1) ? ds.y : (z == 2) ? ds.z : ds.w;
    const unsigned short* A = powb + (size_t)an * MS;
    const unsigned short* B = powb + (size_t)at * MS;
    unsigned short*       D = powb + (size_t)ad * MS;
    __shared__ unsigned short As[2][128][LDK];
    __shared__ unsigned short Bs2[2][128][LDK];
    f32x4 acc[4][4] = {};
    const int row0 = blockIdx.y * 128, n0 = blockIdx.x * 128;
    gemm2_mainloop<SK_BF16_NAT, SK_BF16_TRANS>(acc, A, NXX, B, NXX, NXX, row0, n0, As, Bs2);
    const int tid = threadIdx.x;
    const int lane = tid & 63, wave = tid >> 6;
    const int wm = (wave >> 1) * 64, wn = (wave & 1) * 64;
    const int l16 = lane & 15, quad = lane >> 4;
#pragma unroll
    for (int fm = 0; fm < 4; ++fm)
#pragma unroll
        for (int fn = 0; fn < 4; ++fn)
#pragma unroll
            for (int r = 0; r < 4; ++r) {
                int m = row0 + wm + fm * 16 + quad * 4 + r;
                int n = n0 + wn + fn * 16 + l16;
                D[(size_t)m * NXX + n] = f2bf(acc[fm][fn][r]);
            }
}

// ---------------------------------------------------------------------------
// Fused Hillis-Steele level + piggybacked power squaring.
// ---------------------------------------------------------------------------
__global__ __launch_bounds__(256) void k_hs_sq(
    const unsigned short* __restrict__ vsrc, unsigned short* __restrict__ vdst,
    const unsigned short* __restrict__ Am, int s,
    unsigned short* __restrict__ powb, int sqa, int sqd)
{
    const int z = blockIdx.z;
    const int tid = threadIdx.x;
    __shared__ unsigned short As[2][128][LDK];
    __shared__ unsigned short Bs2[2][128][LDK];
    const int lane = tid & 63, wave = tid >> 6;
    const int wm = (wave >> 1) * 64, wn = (wave & 1) * 64;
    const int l16 = lane & 15, quad = lane >> 4;

    if (z >= NC) {
        const unsigned short* Aq = powb + (size_t)sqa * MS;
        unsigned short*       Dq = powb + (size_t)sqd * MS;
        const int row0 = (blockIdx.y + 2 * (z - NC)) * 128;
        const int n0   = blockIdx.x * 128;
        f32x4 acc[4][4] = {};
        gemm2_mainloop<SK_BF16_NAT, SK_BF16_TRANS>(acc, Aq, NXX, Aq, NXX, NXX, row0, n0, As, Bs2);
#pragma unroll
        for (int fm = 0; fm < 4; ++fm)
#pragma unroll
            for (int fn = 0; fn < 4; ++fn)
#pragma unroll
                for (int r = 0; r < 4; ++r) {
                    int m = row0 + wm + fm * 16 + quad * 4 + r;
                    int n = n0 + wn + fn * 16 + l16;
                    Dq[(size_t)m * NXX + n] = f2bf(acc[fm][fn][r]);
                }
        return;
    }

    const int c = z;
    const int row0 = blockIdx.y * 128, n0 = blockIdx.x * 128;
    if (c < s) {
        const unsigned short* sp = vsrc + (size_t)c * BS;
        unsigned short*       dp = vdst + (size_t)c * BS;
#pragma unroll
        for (int i = 0; i < 8; ++i) {
            int idx = tid + i * 256;
            int r = idx >> 4, cc = (idx & 15) << 3;
            *(ushort8*)(dp + (size_t)(row0 + r) * NXX + n0 + cc) =
                *(const ushort8*)(sp + (size_t)(row0 + r) * NXX + n0 + cc);
        }
        return;
    }
    f32x4 acc[4][4] = {};
    gemm2_mainloop<SK_BF16_NAT, SK_BF16_NAT>(acc, vsrc + (size_t)(c - s) * BS, NXX,
                                             Am, NXX, NXX, row0, n0, As, Bs2);
    const unsigned short* Cp = vsrc + (size_t)c * BS;
    unsigned short*       Dp = vdst + (size_t)c * BS;
#pragma unroll
    for (int fm = 0; fm < 4; ++fm)
#pragma unroll
        for (int fn = 0; fn < 4; ++fn)
#pragma unroll
            for (int r = 0; r < 4; ++r) {
                int m = row0 + wm + fm * 16 + quad * 4 + r;
                int n = n0 + wn + fn * 16 + l16;
                float v = acc[fm][fn][r] + bf2f(Cp[(size_t)m * NXX + n]);
                Dp[(size_t)m * NXX + n] = f2bf(v);
            }
}

// ---------------------------------------------------------------------------
// Seed-correction GEMM:  X[t] += vA[t/8] @ W^{(t%8)+1};  Y = X[:,:,511]
// ---------------------------------------------------------------------------
__global__ __launch_bounds__(256) void k_xcorr(
    const unsigned short* __restrict__ vA, const unsigned short* __restrict__ powb,
    float* __restrict__ X, float* __restrict__ Y)
{
    const int t = blockIdx.z;
    const int c = t >> 3, j = t & 7;
    const int row0 = blockIdx.y * 128, n0 = blockIdx.x * 128;
    __shared__ unsigned short As[2][128][LDK];
    __shared__ unsigned short Bs2[2][128][LDK];
    f32x4 acc[4][4] = {};
    gemm2_mainloop<SK_BF16_NAT, SK_BF16_NAT>(acc, vA + (size_t)c * BS, NXX,
                                             powb + (size_t)j * MS, NXX, NXX,
                                             row0, n0, As, Bs2);
    const int tid = threadIdx.x;
    const int lane = tid & 63, wave = tid >> 6;
    const int wm = (wave >> 1) * 64, wn = (wave & 1) * 64;
    const int l16 = lane & 15, quad = lane >> 4;
    float* Xt = X + (size_t)t * BB * NXX;
#pragma unroll
    for (int fm = 0; fm < 4; ++fm)
#pragma unroll
        for (int fn = 0; fn < 4; ++fn)
#pragma unroll
            for (int r = 0; r < 4; ++r) {
                int m = row0 + wm + fm * 16 + quad * 4 + r;
                int n = n0 + wn + fn * 16 + l16;
                float v = acc[fm][fn][r] + Xt[(size_t)m * NXX + n];
                Xt[(size_t)m * NXX + n] = v;
                if (n == NXX - 1) Y[(size_t)t * BB + m] = v;
            }
}

// ---------------------------------------------------------------------------
// Pass A: fused per-chunk zero-init recurrence, 16 waves/block.
// Hand-pipelined b-operand stream: two 8-frag register banks (A*, B*); each
// group issues the NEXT group's 8 global loads, then sched_barrier(0) pins
// them above the CURRENT group's MFMAs -> ~8 loads in flight hide L2 latency
// (compiler at VGPR=52 serialized them; this forces ~32 more VGPRs of ILP).
// LDS strides 536/152/88 (row-step 12 dw mod 32 -> conflict-free row perm).
// ---------------------------------------------------------------------------
#define SMF(f, g, a, b) \
    acc[f][g] = __builtin_amdgcn_mfma_f32_16x16x32_bf16(a, b, acc[f][g], 0, 0, 0)
#define KK4(aS, kkv, b0, b1) { \
    short8 xa0 = *(const short8*)&aS[l16][(kkv) * 32 + quad * 8]; \
    short8 xa1 = *(const short8*)&aS[16 + l16][(kkv) * 32 + quad * 8]; \
    SMF(0, 0, xa0, b0); SMF(1, 0, xa1, b0); \
    SMF(0, 1, xa0, b1); SMF(1, 1, xa1, b1); }
#define LDP(dst, base, off) dst = *(const short8*)((base) + (off))
#define FENCE() __builtin_amdgcn_sched_barrier(0)

__global__ __launch_bounds__(1024, 4) void k_scanA(
    const float* __restrict__ U, const float* __restrict__ Dm,
    const unsigned short* __restrict__ Bwb, const unsigned short* __restrict__ Ewb,
    const unsigned short* __restrict__ Wt,
    unsigned short* __restrict__ Gout,
    float* __restrict__ X)
{
    const int c   = blockIdx.x;          // chunk 0..31
    const int r0  = blockIdx.y * 32;     // batch-row base
    const int tid = threadIdx.x;         // 0..1023
    const int lane = tid & 63, wave = tid >> 6;   // wave 0..15
    const int l16 = lane & 15, quad = lane >> 4;

    __shared__ unsigned short Sb[2][32][536];   // state bf16, double-buffered
    __shared__ unsigned short Ub[2][32][152];   // U tile bf16
    __shared__ unsigned short Db[2][32][88];    // D tile bf16

    const int srow = tid >> 5;           // 0..31
    const int su   = (tid & 31) * 4;     // U: 4 floats
    const int sd   = (tid & 31) * 2;     // D: 2 floats

    // prologue: stage step 0 U/D into buffer 0
    {
        const float* up = U + ((size_t)(c * CL) * BB + r0 + srow) * NUU + su;
        float4 a0 = *(const float4*)up;
        ushort4v h0 = { f2bf(a0.x), f2bf(a0.y), f2bf(a0.z), f2bf(a0.w) };
        *(ushort4v*)&Ub[0][srow][su] = h0;
        const float* dp = Dm + ((size_t)(c * CL) * BB + r0 + srow) * NDD + sd;
        float2 b0 = *(const float2*)dp;
        unsigned pk = (unsigned)f2bf(b0.x) | ((unsigned)f2bf(b0.y) << 16);
        *(unsigned*)&Db[0][srow][sd] = pk;
    }

    const int nw    = wave * 32 + l16;
    const int woff0  = nw * NXX + quad * 8,  woff1  = (nw + 16) * NXX + quad * 8;
    const int bwoff0 = nw * NUU + quad * 8,  bwoff1 = (nw + 16) * NUU + quad * 8;
    const int ewoff0 = nw * NDD + quad * 8,  ewoff1 = (nw + 16) * NDD + quad * 8;

    f32x4 acc[2][2];
    short8 A0, A1, A2, A3, A4, A5, A6, A7;
    short8 B0, B1, B2, B3, B4, B5, B6, B7;

    // ---------------- step 0 (inj only, peeled) ----------------
    {
        const int t = c * CL;
        __syncthreads();
        float4 pu = *(const float4*)(U + ((size_t)(t + 1) * BB + r0 + srow) * NUU + su);
        float2 pd = *(const float2*)(Dm + ((size_t)(t + 1) * BB + r0 + srow) * NDD + sd);
#pragma unroll
        for (int f = 0; f < 2; ++f)
#pragma unroll
            for (int g = 0; g < 2; ++g) acc[f][g] = (f32x4){0.f, 0.f, 0.f, 0.f};

        LDP(A0, Bwb, bwoff0);       LDP(A1, Bwb, bwoff1);
        LDP(A2, Bwb, bwoff0 + 32);  LDP(A3, Bwb, bwoff1 + 32);
        LDP(A4, Bwb, bwoff0 + 64);  LDP(A5, Bwb, bwoff1 + 64);
        LDP(A6, Bwb, bwoff0 + 96);  LDP(A7, Bwb, bwoff1 + 96);
        LDP(B0, Ewb, ewoff0);       LDP(B1, Ewb, ewoff1);
        LDP(B2, Ewb, ewoff0 + 32);  LDP(B3, Ewb, ewoff1 + 32);
        FENCE();
        KK4(Ub[0], 0, A0, A1); KK4(Ub[0], 1, A2, A3);
        KK4(Ub[0], 2, A4, A5); KK4(Ub[0], 3, A6, A7);
        KK4(Db[0], 0, B0, B1); KK4(Db[0], 1, B2, B3);

#pragma unroll
        for (int f = 0; f < 2; ++f)
#pragma unroll
            for (int g = 0; g < 2; ++g) {
                int n = wave * 32 + g * 16 + l16;
#pragma unroll
                for (int rr = 0; rr < 4; ++rr) {
                    int mr = f * 16 + quad * 4 + rr;
                    float v = acc[f][g][rr];
                    Sb[1][mr][n] = f2bf(v);
                    X[((size_t)t * BB + r0 + mr) * NXX + n] = v;
                }
            }
        ushort4v h0 = { f2bf(pu.x), f2bf(pu.y), f2bf(pu.z), f2bf(pu.w) };
        *(ushort4v*)&Ub[1][srow][su] = h0;
        unsigned pk = (unsigned)f2bf(pd.x) | ((unsigned)f2bf(pd.y) << 16);
        *(unsigned*)&Db[1][srow][sd] = pk;
    }

    // ---------------- steps 1..7 (full K=704 pipeline) ----------------
    for (int j = 1; j < CL; ++j) {
        const int t   = c * CL + j;
        const int cur = j & 1, nxt = cur ^ 1;

        __syncthreads();   // Sb/Ub/Db[cur] from previous step now visible

        float4 pu; float2 pd;
        if (j + 1 < CL) {
            pu = *(const float4*)(U + ((size_t)(t + 1) * BB + r0 + srow) * NUU + su);
            pd = *(const float2*)(Dm + ((size_t)(t + 1) * BB + r0 + srow) * NDD + sd);
        }
#pragma unroll
        for (int f = 0; f < 2; ++f)
#pragma unroll
            for (int g = 0; g < 2; ++g) acc[f][g] = (f32x4){0.f, 0.f, 0.f, 0.f};

        // group 1: issue U b-frags; nothing to compute yet
        LDP(A0, Bwb, bwoff0);       LDP(A1, Bwb, bwoff1);
        LDP(A2, Bwb, bwoff0 + 32);  LDP(A3, Bwb, bwoff1 + 32);
        LDP(A4, Bwb, bwoff0 + 64);  LDP(A5, Bwb, bwoff1 + 64);
        LDP(A6, Bwb, bwoff0 + 96);  LDP(A7, Bwb, bwoff1 + 96);
        FENCE();
        // group 2: issue Ew + W kk0..1 while computing inj-U
        LDP(B0, Ewb, ewoff0);       LDP(B1, Ewb, ewoff1);
        LDP(B2, Ewb, ewoff0 + 32);  LDP(B3, Ewb, ewoff1 + 32);
        LDP(B4, Wt, woff0);         LDP(B5, Wt, woff1);
        LDP(B6, Wt, woff0 + 32);    LDP(B7, Wt, woff1 + 32);
        FENCE();
        KK4(Ub[cur], 0, A0, A1); KK4(Ub[cur], 1, A2, A3);
        KK4(Ub[cur], 2, A4, A5); KK4(Ub[cur], 3, A6, A7);
        // group 3: issue W kk2..5 while computing inj-D + W kk0..1
        LDP(A0, Wt, woff0 + 64);    LDP(A1, Wt, woff1 + 64);
        LDP(A2, Wt, woff0 + 96);    LDP(A3, Wt, woff1 + 96);
        LDP(A4, Wt, woff0 + 128);   LDP(A5, Wt, woff1 + 128);
        LDP(A6, Wt, woff0 + 160);   LDP(A7, Wt, woff1 + 160);
        FENCE();
        KK4(Db[cur], 0, B0, B1); KK4(Db[cur], 1, B2, B3);
        KK4(Sb[cur], 0, B4, B5); KK4(Sb[cur], 1, B6, B7);
        // group 4: issue W kk6..9 while computing W kk2..5
        LDP(B0, Wt, woff0 + 192);   LDP(B1, Wt, woff1 + 192);
        LDP(B2, Wt, woff0 + 224);   LDP(B3, Wt, woff1 + 224);
        LDP(B4, Wt, woff0 + 256);   LDP(B5, Wt, woff1 + 256);
        LDP(B6, Wt, woff0 + 288);   LDP(B7, Wt, woff1 + 288);
        FENCE();
        KK4(Sb[cur], 2, A0, A1); KK4(Sb[cur], 3, A2, A3);
        KK4(Sb[cur], 4, A4, A5); KK4(Sb[cur], 5, A6, A7);
        // group 5: issue W kk10..13 while computing W kk6..9
        LDP(A0, Wt, woff0 + 320);   LDP(A1, Wt, woff1 + 320);
        LDP(A2, Wt, woff0 + 352);   LDP(A3, Wt, woff1 + 352);
        LDP(A4, Wt, woff0 + 384);   LDP(A5, Wt, woff1 + 384);
        LDP(A6, Wt, woff0 + 416);   LDP(A7, Wt, woff1 + 416);
        FENCE();
        KK4(Sb[cur], 6, B0, B1); KK4(Sb[cur], 7, B2, B3);
        KK4(Sb[cur], 8, B4, B5); KK4(Sb[cur], 9, B6, B7);
        // group 6: issue W kk14..15 while computing W kk10..13
        LDP(B0, Wt, woff0 + 448);   LDP(B1, Wt, woff1 + 448);
        LDP(B2, Wt, woff0 + 480);   LDP(B3, Wt, woff1 + 480);
        FENCE();
        KK4(Sb[cur], 10, A0, A1); KK4(Sb[cur], 11, A2, A3);
        KK4(Sb[cur], 12, A4, A5); KK4(Sb[cur], 13, A6, A7);
        KK4(Sb[cur], 14, B0, B1); KK4(Sb[cur], 15, B2, B3);

        // ---- write new state to OTHER buffer + X (f32) ----
#pragma unroll
        for (int f = 0; f < 2; ++f)
#pragma unroll
            for (int g = 0; g < 2; ++g) {
                int n = wave * 32 + g * 16 + l16;
#pragma unroll
                for (int rr = 0; rr < 4; ++rr) {
                    int mr = f * 16 + quad * 4 + rr;
                    float v = acc[f][g][rr];
                    unsigned short hb = f2bf(v);
                    Sb[nxt][mr][n] = hb;
                    X[((size_t)t * BB + r0 + mr) * NXX + n] = v;
                    if (j == CL - 1)
                        Gout[((size_t)(c + 1) * BB + r0 + mr) * NXX + n] = hb;
                }
            }
        if (j + 1 < CL) {
            ushort4v h0 = { f2bf(pu.x), f2bf(pu.y), f2bf(pu.z), f2bf(pu.w) };
            *(ushort4v*)&Ub[nxt][srow][su] = h0;
            unsigned pk = (unsigned)f2bf(pd.x) | ((unsigned)f2bf(pd.y) << 16);
            *(unsigned*)&Db[nxt][srow][sd] = pk;
        }
    }
}
#undef SMF
#undef KK4
#undef LDP
#undef FENCE

// ---------------------------------------------------------------------------
extern "C" void kernel_launch(void* const* d_in, const int* in_sizes, int n_in,
                              void* d_out, int out_size, void* d_ws, size_t ws_size,
                              hipStream_t stream)
{
    const float* x   = (const float*)d_in[0];
    const float* U   = (const float*)d_in[1];
    const float* Dm  = (const float*)d_in[2];
    const float* Aw  = (const float*)d_in[3];
    const float* Asc = (const float*)d_in[4];
    const float* Bw  = (const float*)d_in[5];
    const float* Ew  = (const float*)d_in[6];

    float* Xout = (float*)d_out;
    float* Yout = Xout + (size_t)TT * BB * NXX;

    // ws layout (bf16): power slots 0..7 = W^{1..8}, 8..11 = W^{16,32,64,128};
    // Bwb 512x128; Ewb 512x64; G 33 slabs; vA 32; vB 32  (~32 MB total)
    unsigned short* powb = (unsigned short*)d_ws;
    unsigned short* Bwb  = powb + (size_t)12 * MS;
    unsigned short* Ewb  = Bwb + (size_t)NXX * NUU;
    unsigned short* Gbuf = Ewb + (size_t)NXX * NDD;
    unsigned short* vA   = Gbuf + (size_t)(NC + 1) * BS;
    unsigned short* vB   = vA + (size_t)NC * BS;

    dim3 blk(256);
    dim3 blkScan(1024);

    k_weff<<<dim3(512), blk, 0, stream>>>(Aw, Asc, powb);
    k_prep<<<dim3(224), blk, 0, stream>>>(Bw, Ew, x, Bwb, Ewb, Gbuf);

    // power products (T-space; slot p-1 = W^p for p=1..8); W^{16..128} ride
    // along inside the HS launches below.
    k_mulN<<<dim3(4, 4, 1), blk, 0, stream>>>(powb,
        make_int4(0, 0, 0, 0), make_int4(0, 0, 0, 0), make_int4(1, 0, 0, 0));
    k_mulN<<<dim3(4, 4, 2), blk, 0, stream>>>(powb,
        make_int4(1, 1, 0, 0), make_int4(0, 1, 0, 0), make_int4(2, 3, 0, 0));
    k_mulN<<<dim3(4, 4, 4), blk, 0, stream>>>(powb,
        make_int4(3, 3, 3, 3), make_int4(0, 1, 2, 3), make_int4(4, 5, 6, 7));

    // Pass A: zero-init chunk scans -> xA into X (f32), chunk-ends into G[1..32]
    k_scanA<<<dim3(NC, 8), blkScan, 0, stream>>>(
        U, Dm, Bwb, Ewb, powb, Gbuf, Xout);

    // Hillis-Steele prefix with piggybacked squarings (W^16..W^128)
    k_hs_sq<<<dim3(4, 2, NC + 2), blk, 0, stream>>>(Gbuf, vA, powb + (size_t)7 * MS, 1,
                                                    powb, 7, 8);
    k_hs_sq<<<dim3(4, 2, NC + 2), blk, 0, stream>>>(vA, vB, powb + (size_t)8 * MS, 2,
                                                    powb, 8, 9);
    k_hs_sq<<<dim3(4, 2, NC + 2), blk, 0, stream>>>(vB, vA, powb + (size_t)9 * MS, 4,
                                                    powb, 9, 10);
    k_hs_sq<<<dim3(4, 2, NC + 2), blk, 0, stream>>>(vA, vB, powb + (size_t)10 * MS, 8,
                                                    powb, 10, 11);
    k_hs_sq<<<dim3(4, 2, NC), blk, 0, stream>>>(vB, vA, powb + (size_t)11 * MS, 16,
                                                powb, 0, 0);

    // Seed-correction GEMM: X[t] += vA[t/8] @ W^{(t%8)+1}; writes Y
    k_xcorr<<<dim3(4, 2, TT), blk, 0, stream>>>(vA, powb, Xout, Yout);
}

// Round 7
// 654.644 us; speedup vs baseline: 1.0438x; 1.0438x over previous
//
#include <hip/hip_runtime.h>
#include <hip/hip_bf16.h>
#include <cstddef>

#define NXX 512
#define NUU 128
#define NDD 64
#define BB  256
#define TT  256
#define CL  4              // steps per chunk (halved: more chunk parallelism)
#define NC  64             // chunks
#define BS  (BB * NXX)     // one slab in elements (256*512)
#define MS  (NXX * NXX)    // one 512x512 matrix in elements
#define LDK 32             // LDS row stride (bf16) for 128x32 staging tiles

typedef __attribute__((ext_vector_type(8))) short short8;
typedef __attribute__((ext_vector_type(8))) unsigned short ushort8;
typedef __attribute__((ext_vector_type(4))) unsigned short ushort4v;
typedef __attribute__((ext_vector_type(4))) float f32x4;

__device__ __forceinline__ unsigned short f2bf(float f) {
    union { float f; unsigned u; } v; v.f = f;
    unsigned r = v.u + 0x7FFFu + ((v.u >> 16) & 1u);   // RNE
    return (unsigned short)(r >> 16);
}
__device__ __forceinline__ float bf2f(unsigned short h) {
    union { unsigned u; float f; } v; v.u = ((unsigned)h) << 16;
    return v.f;
}

// ---------------------------------------------------------------------------
// 2-phase double-buffered 128x128-tile GEMM machinery (mulN / hs / xcorr).
// ---------------------------------------------------------------------------
enum StageKind { SK_BF16_NAT, SK_BF16_TRANS };

__device__ __forceinline__ void stage_nat(const unsigned short* s, int ld, int r0,
                                          int k0, unsigned short (*S)[LDK])
{
    const int tid = threadIdx.x;
    const int wave = tid >> 6, lane = tid & 63;
#pragma unroll
    for (int i = 0; i < 2; ++i) {
        int rb = wave * 16 + i * 64;      // wave-uniform row base
        int r  = rb + (lane >> 2);
        int c  = (lane & 3) << 3;
        const unsigned short* g = s + (size_t)(r0 + r) * ld + k0 + c;
        __builtin_amdgcn_global_load_lds(
            (const __attribute__((address_space(1))) void*)g,
            (__attribute__((address_space(3))) void*)&S[rb][0],
            16, 0, 0);
    }
}
__device__ __forceinline__ ushort8 ldT(const unsigned short* s, int ld, int r0,
                                       int k0, int i)
{
    int idx = threadIdx.x + i * 256;
    int m   = idx >> 4;                   // 0..31 contraction row
    int c   = (idx & 15) << 3;            // 0..120 output col
    return *(const ushort8*)(s + (size_t)(k0 + m) * ld + r0 + c);
}
__device__ __forceinline__ void wrT(ushort8 v, int i, unsigned short (*S)[LDK])
{
    int idx = threadIdx.x + i * 256;
    int m   = idx >> 4;
    int c   = (idx & 15) << 3;
#pragma unroll
    for (int j = 0; j < 8; ++j) S[c + j][m] = v[j];
}

template<StageKind AK, StageKind BK>
__device__ __forceinline__ void gemm2_mainloop(
    f32x4 (&acc)[4][4],
    const void* A, int lda, const void* B, int ldb,
    int K, int row0, int n0,
    unsigned short (*As)[128][LDK], unsigned short (*Bs)[128][LDK])
{
    const int tid  = threadIdx.x;
    const int lane = tid & 63;
    const int wave = tid >> 6;
    const int wm   = (wave >> 1) * 64;
    const int wn   = (wave & 1) * 64;
    const int l16  = lane & 15;
    const int quad = lane >> 4;
    const unsigned short* Ap = (const unsigned short*)A;
    const unsigned short* Bp = (const unsigned short*)B;
    const int NT = K >> 5;

    if constexpr (AK == SK_BF16_NAT) stage_nat(Ap, lda, row0, 0, As[0]);
    else { wrT(ldT(Ap, lda, row0, 0, 0), 0, As[0]); wrT(ldT(Ap, lda, row0, 0, 1), 1, As[0]); }
    if constexpr (BK == SK_BF16_NAT) stage_nat(Bp, ldb, n0, 0, Bs[0]);
    else { wrT(ldT(Bp, ldb, n0, 0, 0), 0, Bs[0]); wrT(ldT(Bp, ldb, n0, 0, 1), 1, Bs[0]); }
    __syncthreads();

    for (int t = 0; t < NT; ++t) {
        const int cur = t & 1, nxt = cur ^ 1;
        const int k1  = (t + 1) << 5;
        ushort8 ta0, ta1, tb0, tb1;
        if (t + 1 < NT) {
            if constexpr (AK == SK_BF16_NAT) stage_nat(Ap, lda, row0, k1, As[nxt]);
            else { ta0 = ldT(Ap, lda, row0, k1, 0); ta1 = ldT(Ap, lda, row0, k1, 1); }
            if constexpr (BK == SK_BF16_NAT) stage_nat(Bp, ldb, n0, k1, Bs[nxt]);
            else { tb0 = ldT(Bp, ldb, n0, k1, 0); tb1 = ldT(Bp, ldb, n0, k1, 1); }
        }
        short8 af[4], bfr[4];
#pragma unroll
        for (int f = 0; f < 4; ++f)
            af[f] = *(const short8*)&As[cur][wm + f * 16 + l16][quad * 8];
#pragma unroll
        for (int f = 0; f < 4; ++f)
            bfr[f] = *(const short8*)&Bs[cur][wn + f * 16 + l16][quad * 8];
#pragma unroll
        for (int fm = 0; fm < 4; ++fm)
#pragma unroll
            for (int fn = 0; fn < 4; ++fn)
                acc[fm][fn] = __builtin_amdgcn_mfma_f32_16x16x32_bf16(
                    af[fm], bfr[fn], acc[fm][fn], 0, 0, 0);
        if (t + 1 < NT) {
            if constexpr (AK == SK_BF16_TRANS) { wrT(ta0, 0, As[nxt]); wrT(ta1, 1, As[nxt]); }
            if constexpr (BK == SK_BF16_TRANS) { wrT(tb0, 0, Bs[nxt]); wrT(tb1, 1, Bs[nxt]); }
        }
        __syncthreads();
    }
}

// ---------------------------------------------------------------------------
// T1[n][k] = (1 - 0.1*sigmoid(Asc[n][k])) * softmax(Aw[n,:])[k]  (bf16 T-layout)
// ---------------------------------------------------------------------------
__global__ __launch_bounds__(256) void k_weff(
    const float* __restrict__ Aw, const float* __restrict__ Asc,
    unsigned short* __restrict__ T1)
{
    const int n   = blockIdx.x;
    const int tid = threadIdx.x;
    const int lane = tid & 63, wave = tid >> 6;
    float v0 = Aw[(size_t)n * NXX + tid];
    float v1 = Aw[(size_t)n * NXX + 256 + tid];
    __shared__ float sred[4];
    float m = fmaxf(v0, v1);
#pragma unroll
    for (int off = 32; off; off >>= 1) m = fmaxf(m, __shfl_down(m, off));
    if (lane == 0) sred[wave] = m;
    __syncthreads();
    if (tid == 0) sred[0] = fmaxf(fmaxf(sred[0], sred[1]), fmaxf(sred[2], sred[3]));
    __syncthreads();
    const float mm = sred[0];
    __syncthreads();
    float e0 = expf(v0 - mm), e1 = expf(v1 - mm);
    float s = e0 + e1;
#pragma unroll
    for (int off = 32; off; off >>= 1) s += __shfl_down(s, off);
    if (lane == 0) sred[wave] = s;
    __syncthreads();
    if (tid == 0) sred[0] = sred[0] + sred[1] + sred[2] + sred[3];
    __syncthreads();
    const float inv = 1.0f / sred[0];
    float sc0 = 1.0f - 0.1f * (1.0f / (1.0f + expf(-Asc[(size_t)n * NXX + tid])));
    float sc1 = 1.0f - 0.1f * (1.0f / (1.0f + expf(-Asc[(size_t)n * NXX + 256 + tid])));
    unsigned short* out = T1 + (size_t)n * NXX;
    out[tid]       = f2bf(sc0 * e0 * inv);
    out[tid + 256] = f2bf(sc1 * e1 * inv);
}

// ---------------------------------------------------------------------------
// elementwise f32->bf16 prep: Bw (512x128), Ew (512x64), x (256x512 -> G slab 0)
// ---------------------------------------------------------------------------
__global__ __launch_bounds__(256) void k_prep(
    const float* __restrict__ Bw, const float* __restrict__ Ew,
    const float* __restrict__ x,
    unsigned short* __restrict__ Bwb, unsigned short* __restrict__ Ewb,
    unsigned short* __restrict__ G0)
{
    int i = (blockIdx.x * 256 + threadIdx.x) * 4;
    const float* src; unsigned short* dst; int k;
    if (i < 65536)       { src = Bw; dst = Bwb; k = i; }
    else if (i < 98304)  { src = Ew; dst = Ewb; k = i - 65536; }
    else                 { src = x;  dst = G0;  k = i - 98304; }
    float4 v = *(const float4*)(src + k);
    ushort4v h = { f2bf(v.x), f2bf(v.y), f2bf(v.z), f2bf(v.w) };
    *(ushort4v*)(dst + k) = h;
}

// ---------------------------------------------------------------------------
// Batched power products in T-space: slot ds[z] = slot ns[z] (NAT) * ts[z] (TRANS)
// T-space product of stored layouts = T_{a+b} (powers commute).
// ---------------------------------------------------------------------------
__global__ __launch_bounds__(256) void k_mulN(unsigned short* __restrict__ powb,
                                              int4 ns, int4 ts, int4 ds)
{
    const int z = blockIdx.z;
    const int an = (z == 0) ? ns.x : (z == 1) ? ns.y : (z == 2) ? ns.z : ns.w;
    const int at = (z == 0) ? ts.x : (z == 1) ? ts.y : (z == 2) ? ts.z : ts.w;
    const int ad = (z == 0) ? ds.x : (z == 1) ? ds.y : (z == 2) ? ds.z : ds.w;
    const unsigned short* A = powb + (size_t)an * MS;
    const unsigned short* B = powb + (size_t)at * MS;
    unsigned short*       D = powb + (size_t)ad * MS;
    __shared__ unsigned short As[2][128][LDK];
    __shared__ unsigned short Bs2[2][128][LDK];
    f32x4 acc[4][4] = {};
    const int row0 = blockIdx.y * 128, n0 = blockIdx.x * 128;
    gemm2_mainloop<SK_BF16_NAT, SK_BF16_TRANS>(acc, A, NXX, B, NXX, NXX, row0, n0, As, Bs2);
    const int tid = threadIdx.x;
    const int lane = tid & 63, wave = tid >> 6;
    const int wm = (wave >> 1) * 64, wn = (wave & 1) * 64;
    const int l16 = lane & 15, quad = lane >> 4;
#pragma unroll
    for (int fm = 0; fm < 4; ++fm)
#pragma unroll
        for (int fn = 0; fn < 4; ++fn)
#pragma unroll
            for (int r = 0; r < 4; ++r) {
                int m = row0 + wm + fm * 16 + quad * 4 + r;
                int n = n0 + wn + fn * 16 + l16;
                D[(size_t)m * NXX + n] = f2bf(acc[fm][fn][r]);
            }
}

// ---------------------------------------------------------------------------
// Fused Hillis-Steele level (over NC=64 chunk-start slabs) + piggybacked
// power squaring.  z < NC: HS slab z; z >= NC: squaring tiles of
// T[sqd] = T[sqa]^2, consumed one launch later.
// ---------------------------------------------------------------------------
__global__ __launch_bounds__(256) void k_hs_sq(
    const unsigned short* __restrict__ vsrc, unsigned short* __restrict__ vdst,
    const unsigned short* __restrict__ Am, int s,
    unsigned short* __restrict__ powb, int sqa, int sqd)
{
    const int z = blockIdx.z;
    const int tid = threadIdx.x;
    __shared__ unsigned short As[2][128][LDK];
    __shared__ unsigned short Bs2[2][128][LDK];
    const int lane = tid & 63, wave = tid >> 6;
    const int wm = (wave >> 1) * 64, wn = (wave & 1) * 64;
    const int l16 = lane & 15, quad = lane >> 4;

    if (z >= NC) {
        const unsigned short* Aq = powb + (size_t)sqa * MS;
        unsigned short*       Dq = powb + (size_t)sqd * MS;
        const int row0 = (blockIdx.y + 2 * (z - NC)) * 128;
        const int n0   = blockIdx.x * 128;
        f32x4 acc[4][4] = {};
        gemm2_mainloop<SK_BF16_NAT, SK_BF16_TRANS>(acc, Aq, NXX, Aq, NXX, NXX, row0, n0, As, Bs2);
#pragma unroll
        for (int fm = 0; fm < 4; ++fm)
#pragma unroll
            for (int fn = 0; fn < 4; ++fn)
#pragma unroll
                for (int r = 0; r < 4; ++r) {
                    int m = row0 + wm + fm * 16 + quad * 4 + r;
                    int n = n0 + wn + fn * 16 + l16;
                    Dq[(size_t)m * NXX + n] = f2bf(acc[fm][fn][r]);
                }
        return;
    }

    const int c = z;
    const int row0 = blockIdx.y * 128, n0 = blockIdx.x * 128;
    if (c < s) {
        const unsigned short* sp = vsrc + (size_t)c * BS;
        unsigned short*       dp = vdst + (size_t)c * BS;
#pragma unroll
        for (int i = 0; i < 8; ++i) {
            int idx = tid + i * 256;
            int r = idx >> 4, cc = (idx & 15) << 3;
            *(ushort8*)(dp + (size_t)(row0 + r) * NXX + n0 + cc) =
                *(const ushort8*)(sp + (size_t)(row0 + r) * NXX + n0 + cc);
        }
        return;
    }
    f32x4 acc[4][4] = {};
    gemm2_mainloop<SK_BF16_NAT, SK_BF16_NAT>(acc, vsrc + (size_t)(c - s) * BS, NXX,
                                             Am, NXX, NXX, row0, n0, As, Bs2);
    const unsigned short* Cp = vsrc + (size_t)c * BS;
    unsigned short*       Dp = vdst + (size_t)c * BS;
#pragma unroll
    for (int fm = 0; fm < 4; ++fm)
#pragma unroll
        for (int fn = 0; fn < 4; ++fn)
#pragma unroll
            for (int r = 0; r < 4; ++r) {
                int m = row0 + wm + fm * 16 + quad * 4 + r;
                int n = n0 + wn + fn * 16 + l16;
                float v = acc[fm][fn][r] + bf2f(Cp[(size_t)m * NXX + n]);
                Dp[(size_t)m * NXX + n] = f2bf(v);
            }
}

// ---------------------------------------------------------------------------
// Seed-correction GEMM:  t = blockIdx.z, c = t/4, j = t%4:
//   X[t] += seed[c] @ W^{j+1};  Y = X[:,:,511]
// ---------------------------------------------------------------------------
__global__ __launch_bounds__(256) void k_xcorr(
    const unsigned short* __restrict__ seeds, const unsigned short* __restrict__ powb,
    float* __restrict__ X, float* __restrict__ Y)
{
    const int t = blockIdx.z;
    const int c = t >> 2, j = t & 3;
    const int row0 = blockIdx.y * 128, n0 = blockIdx.x * 128;
    __shared__ unsigned short As[2][128][LDK];
    __shared__ unsigned short Bs2[2][128][LDK];
    f32x4 acc[4][4] = {};
    gemm2_mainloop<SK_BF16_NAT, SK_BF16_NAT>(acc, seeds + (size_t)c * BS, NXX,
                                             powb + (size_t)j * MS, NXX, NXX,
                                             row0, n0, As, Bs2);
    const int tid = threadIdx.x;
    const int lane = tid & 63, wave = tid >> 6;
    const int wm = (wave >> 1) * 64, wn = (wave & 1) * 64;
    const int l16 = lane & 15, quad = lane >> 4;
    float* Xt = X + (size_t)t * BB * NXX;
#pragma unroll
    for (int fm = 0; fm < 4; ++fm)
#pragma unroll
        for (int fn = 0; fn < 4; ++fn)
#pragma unroll
            for (int r = 0; r < 4; ++r) {
                int m = row0 + wm + fm * 16 + quad * 4 + r;
                int n = n0 + wn + fn * 16 + l16;
                float v = acc[fm][fn][r] + Xt[(size_t)m * NXX + n];
                Xt[(size_t)m * NXX + n] = v;
                if (n == NXX - 1) Y[(size_t)t * BB + m] = v;
            }
}

// ---------------------------------------------------------------------------
// Pass A: fused per-chunk zero-init recurrence. Block = (chunk c, 32 rows),
// 1024 threads (16 waves). CL=4 serial steps; NC=64 chunks -> grid 512 blocks
// = 2 blocks/CU co-resident (LDS 46.6KB, VGPR<=64 via launch_bounds(1024,8)):
// two independent serial chains per SIMD hide each other's load latency, and
// the serial depth is halved. Proven round-2/4 single-buffer inner structure.
// Writes every step's state to X (f32) and chunk-end state to Gout slab c+1.
// ---------------------------------------------------------------------------
__global__ __launch_bounds__(1024, 8) void k_scanA(
    const float* __restrict__ U, const float* __restrict__ Dm,
    const unsigned short* __restrict__ Bwb, const unsigned short* __restrict__ Ewb,
    const unsigned short* __restrict__ Wt,
    unsigned short* __restrict__ Gout,
    float* __restrict__ X)
{
    const int c   = blockIdx.x;          // chunk 0..63
    const int r0  = blockIdx.y * 32;     // batch-row base
    const int tid = threadIdx.x;         // 0..1023
    const int lane = tid & 63, wave = tid >> 6;   // wave 0..15
    const int l16 = lane & 15, quad = lane >> 4;

    __shared__ unsigned short Sb[32][520];   // state bf16 (pad 8 -> bank rot)
    __shared__ unsigned short Ub[32][136];   // U tile bf16
    __shared__ unsigned short Db[32][72];    // D tile bf16

    // per-lane 32-bit element offsets for the 2 n-frags of this wave
    int woff[2], bwoff[2], ewoff[2];
#pragma unroll
    for (int g = 0; g < 2; ++g) {
        int n = wave * 32 + g * 16 + l16;
        woff[g]  = n * NXX + quad * 8;
        bwoff[g] = n * NUU + quad * 8;
        ewoff[g] = n * NDD + quad * 8;
    }

    f32x4 acc[2][2];

    for (int j = 0; j < CL; ++j) {
        const int t = c * CL + j;
        // ---- stage U (32x128) and D (32x64) f32 -> bf16 into LDS ----
        {
            int row = tid >> 5;               // 0..31
            int uc  = (tid & 31) * 4;         // 4 floats -> 128 cols
            const float* up = U + ((size_t)t * BB + r0 + row) * NUU + uc;
            float4 a0 = *(const float4*)(up);
            ushort4v h0 = { f2bf(a0.x), f2bf(a0.y), f2bf(a0.z), f2bf(a0.w) };
            *(ushort4v*)&Ub[row][uc] = h0;
            int dc = (tid & 31) * 2;          // 2 floats -> 64 cols
            const float* dp = Dm + ((size_t)t * BB + r0 + row) * NDD + dc;
            float2 b0 = *(const float2*)(dp);
            unsigned pk = (unsigned)f2bf(b0.x) | ((unsigned)f2bf(b0.y) << 16);
            *(unsigned*)&Db[row][dc] = pk;
        }
        __syncthreads();   // staging (and prev-step Sb writes) visible

#pragma unroll
        for (int f = 0; f < 2; ++f)
#pragma unroll
            for (int g = 0; g < 2; ++g) acc[f][g] = (f32x4){0.f, 0.f, 0.f, 0.f};

        // ---- inj: U @ Bw^T  (K=128) ----
#pragma unroll
        for (int kk = 0; kk < 4; ++kk) {
            short8 a0 = *(const short8*)&Ub[l16][kk * 32 + quad * 8];
            short8 a1 = *(const short8*)&Ub[16 + l16][kk * 32 + quad * 8];
#pragma unroll
            for (int g = 0; g < 2; ++g) {
                short8 b = *(const short8*)(Bwb + bwoff[g] + kk * 32);
                acc[0][g] = __builtin_amdgcn_mfma_f32_16x16x32_bf16(a0, b, acc[0][g], 0, 0, 0);
                acc[1][g] = __builtin_amdgcn_mfma_f32_16x16x32_bf16(a1, b, acc[1][g], 0, 0, 0);
            }
        }
        // ---- inj: D @ Ew^T  (K=64) ----
#pragma unroll
        for (int kk = 0; kk < 2; ++kk) {
            short8 a0 = *(const short8*)&Db[l16][kk * 32 + quad * 8];
            short8 a1 = *(const short8*)&Db[16 + l16][kk * 32 + quad * 8];
#pragma unroll
            for (int g = 0; g < 2; ++g) {
                short8 b = *(const short8*)(Ewb + ewoff[g] + kk * 32);
                acc[0][g] = __builtin_amdgcn_mfma_f32_16x16x32_bf16(a0, b, acc[0][g], 0, 0, 0);
                acc[1][g] = __builtin_amdgcn_mfma_f32_16x16x32_bf16(a1, b, acc[1][g], 0, 0, 0);
            }
        }
        // ---- state @ W  (K=512) ----
        if (j > 0) {
#pragma unroll
            for (int kk = 0; kk < 16; ++kk) {
                short8 a0 = *(const short8*)&Sb[l16][kk * 32 + quad * 8];
                short8 a1 = *(const short8*)&Sb[16 + l16][kk * 32 + quad * 8];
#pragma unroll
                for (int g = 0; g < 2; ++g) {
                    short8 b = *(const short8*)(Wt + woff[g] + kk * 32);
                    acc[0][g] = __builtin_amdgcn_mfma_f32_16x16x32_bf16(a0, b, acc[0][g], 0, 0, 0);
                    acc[1][g] = __builtin_amdgcn_mfma_f32_16x16x32_bf16(a1, b, acc[1][g], 0, 0, 0);
                }
            }
        }
        __syncthreads();   // all reads of Sb done before overwrite

        // ---- write new state + xA (f32) ----
#pragma unroll
        for (int f = 0; f < 2; ++f)
#pragma unroll
            for (int g = 0; g < 2; ++g) {
                int n = wave * 32 + g * 16 + l16;
#pragma unroll
                for (int rr = 0; rr < 4; ++rr) {
                    int mr = f * 16 + quad * 4 + rr;
                    float v = acc[f][g][rr];
                    unsigned short hb = f2bf(v);
                    Sb[mr][n] = hb;
                    X[((size_t)t * BB + r0 + mr) * NXX + n] = v;
                    if (j == CL - 1)
                        Gout[((size_t)(c + 1) * BB + r0 + mr) * NXX + n] = hb;
                }
            }
    }
}

// ---------------------------------------------------------------------------
extern "C" void kernel_launch(void* const* d_in, const int* in_sizes, int n_in,
                              void* d_out, int out_size, void* d_ws, size_t ws_size,
                              hipStream_t stream)
{
    const float* x   = (const float*)d_in[0];
    const float* U   = (const float*)d_in[1];
    const float* Dm  = (const float*)d_in[2];
    const float* Aw  = (const float*)d_in[3];
    const float* Asc = (const float*)d_in[4];
    const float* Bw  = (const float*)d_in[5];
    const float* Ew  = (const float*)d_in[6];

    float* Xout = (float*)d_out;
    float* Yout = Xout + (size_t)TT * BB * NXX;

    // ws layout (bf16): power slots 0..3 = W^{1..4}, 4..8 = W^{8,16,32,64,128};
    // Bwb 512x128; Ewb 512x64; G 65 slabs; vA 64 slabs  (~39 MB total)
    unsigned short* powb = (unsigned short*)d_ws;
    unsigned short* Bwb  = powb + (size_t)9 * MS;
    unsigned short* Ewb  = Bwb + (size_t)NXX * NUU;
    unsigned short* Gbuf = Ewb + (size_t)NXX * NDD;
    unsigned short* vA   = Gbuf + (size_t)(NC + 1) * BS;

    dim3 blk(256);
    dim3 blkScan(1024);

    k_weff<<<dim3(512), blk, 0, stream>>>(Aw, Asc, powb);
    k_prep<<<dim3(224), blk, 0, stream>>>(Bw, Ew, x, Bwb, Ewb, Gbuf);

    // power products: slots 0..3 = W^1..W^4 (xcorr + HS level 1);
    // W^{8..128} ride along inside the HS launches below.
    k_mulN<<<dim3(4, 4, 1), blk, 0, stream>>>(powb,
        make_int4(0, 0, 0, 0), make_int4(0, 0, 0, 0), make_int4(1, 0, 0, 0));
    k_mulN<<<dim3(4, 4, 2), blk, 0, stream>>>(powb,
        make_int4(1, 1, 0, 0), make_int4(0, 1, 0, 0), make_int4(2, 3, 0, 0));

    // Pass A: zero-init chunk scans (4 steps, 512 blocks = 2/CU)
    //   -> xA into X (f32), chunk-ends into G[1..64]
    k_scanA<<<dim3(NC, 8), blkScan, 0, stream>>>(
        U, Dm, Bwb, Ewb, powb, Gbuf, Xout);

    // Hillis-Steele prefix over 64 chunk-start slabs, ping-pong G <-> vA,
    // with piggybacked squarings W^8..W^128.  Final seeds land in G.
    k_hs_sq<<<dim3(4, 2, NC + 2), blk, 0, stream>>>(Gbuf, vA, powb + (size_t)3 * MS, 1,
                                                    powb, 3, 4);
    k_hs_sq<<<dim3(4, 2, NC + 2), blk, 0, stream>>>(vA, Gbuf, powb + (size_t)4 * MS, 2,
                                                    powb, 4, 5);
    k_hs_sq<<<dim3(4, 2, NC + 2), blk, 0, stream>>>(Gbuf, vA, powb + (size_t)5 * MS, 4,
                                                    powb, 5, 6);
    k_hs_sq<<<dim3(4, 2, NC + 2), blk, 0, stream>>>(vA, Gbuf, powb + (size_t)6 * MS, 8,
                                                    powb, 6, 7);
    k_hs_sq<<<dim3(4, 2, NC + 2), blk, 0, stream>>>(Gbuf, vA, powb + (size_t)7 * MS, 16,
                                                    powb, 7, 8);
    k_hs_sq<<<dim3(4, 2, NC), blk, 0, stream>>>(vA, Gbuf, powb + (size_t)8 * MS, 32,
                                                powb, 0, 0);

    // Seed-correction GEMM: X[t] += seed[t/4] @ W^{(t%4)+1}; writes Y
    k_xcorr<<<dim3(4, 2, TT), blk, 0, stream>>>(Gbuf, powb, Xout, Yout);
}

// Round 9
// 573.345 us; speedup vs baseline: 1.1918x; 1.1418x over previous
//
#include <hip/hip_runtime.h>
#include <hip/hip_bf16.h>
#include <cstddef>

#define NXX 512
#define NUU 128
#define NDD 64
#define BB  256
#define TT  256
#define CL  4              // steps per chunk
#define NC  64             // chunks
#define BS  (BB * NXX)     // one slab in elements (256*512)
#define MS  (NXX * NXX)    // one 512x512 matrix in elements
#define LDK 32             // LDS row stride (bf16) for 128x32 staging tiles

typedef __attribute__((ext_vector_type(8))) short short8;
typedef __attribute__((ext_vector_type(8))) unsigned short ushort8;
typedef __attribute__((ext_vector_type(4))) unsigned short ushort4v;
typedef __attribute__((ext_vector_type(4))) float f32x4;

__device__ __forceinline__ unsigned short f2bf(float f) {
    union { float f; unsigned u; } v; v.f = f;
    unsigned r = v.u + 0x7FFFu + ((v.u >> 16) & 1u);   // RNE
    return (unsigned short)(r >> 16);
}
__device__ __forceinline__ float bf2f(unsigned short h) {
    union { unsigned u; float f; } v; v.u = ((unsigned)h) << 16;
    return v.f;
}

// ---------------------------------------------------------------------------
// 2-phase double-buffered 128x128-tile GEMM machinery (mulN / hs / xcorr).
// ---------------------------------------------------------------------------
enum StageKind { SK_BF16_NAT, SK_BF16_TRANS };

__device__ __forceinline__ void stage_nat(const unsigned short* s, int ld, int r0,
                                          int k0, unsigned short (*S)[LDK])
{
    const int tid = threadIdx.x;
    const int wave = tid >> 6, lane = tid & 63;
#pragma unroll
    for (int i = 0; i < 2; ++i) {
        int rb = wave * 16 + i * 64;      // wave-uniform row base
        int r  = rb + (lane >> 2);
        int c  = (lane & 3) << 3;
        const unsigned short* g = s + (size_t)(r0 + r) * ld + k0 + c;
        __builtin_amdgcn_global_load_lds(
            (const __attribute__((address_space(1))) void*)g,
            (__attribute__((address_space(3))) void*)&S[rb][0],
            16, 0, 0);
    }
}
__device__ __forceinline__ ushort8 ldT(const unsigned short* s, int ld, int r0,
                                       int k0, int i)
{
    int idx = threadIdx.x + i * 256;
    int m   = idx >> 4;                   // 0..31 contraction row
    int c   = (idx & 15) << 3;            // 0..120 output col
    return *(const ushort8*)(s + (size_t)(k0 + m) * ld + r0 + c);
}
__device__ __forceinline__ void wrT(ushort8 v, int i, unsigned short (*S)[LDK])
{
    int idx = threadIdx.x + i * 256;
    int m   = idx >> 4;
    int c   = (idx & 15) << 3;
#pragma unroll
    for (int j = 0; j < 8; ++j) S[c + j][m] = v[j];
}

template<StageKind AK, StageKind BK>
__device__ __forceinline__ void gemm2_mainloop(
    f32x4 (&acc)[4][4],
    const void* A, int lda, const void* B, int ldb,
    int K, int row0, int n0,
    unsigned short (*As)[128][LDK], unsigned short (*Bs)[128][LDK])
{
    const int tid  = threadIdx.x;
    const int lane = tid & 63;
    const int wave = tid >> 6;
    const int wm   = (wave >> 1) * 64;
    const int wn   = (wave & 1) * 64;
    const int l16  = lane & 15;
    const int quad = lane >> 4;
    const unsigned short* Ap = (const unsigned short*)A;
    const unsigned short* Bp = (const unsigned short*)B;
    const int NT = K >> 5;

    if constexpr (AK == SK_BF16_NAT) stage_nat(Ap, lda, row0, 0, As[0]);
    else { wrT(ldT(Ap, lda, row0, 0, 0), 0, As[0]); wrT(ldT(Ap, lda, row0, 0, 1), 1, As[0]); }
    if constexpr (BK == SK_BF16_NAT) stage_nat(Bp, ldb, n0, 0, Bs[0]);
    else { wrT(ldT(Bp, ldb, n0, 0, 0), 0, Bs[0]); wrT(ldT(Bp, ldb, n0, 0, 1), 1, Bs[0]); }
    __syncthreads();

    for (int t = 0; t < NT; ++t) {
        const int cur = t & 1, nxt = cur ^ 1;
        const int k1  = (t + 1) << 5;
        ushort8 ta0, ta1, tb0, tb1;
        if (t + 1 < NT) {
            if constexpr (AK == SK_BF16_NAT) stage_nat(Ap, lda, row0, k1, As[nxt]);
            else { ta0 = ldT(Ap, lda, row0, k1, 0); ta1 = ldT(Ap, lda, row0, k1, 1); }
            if constexpr (BK == SK_BF16_NAT) stage_nat(Bp, ldb, n0, k1, Bs[nxt]);
            else { tb0 = ldT(Bp, ldb, n0, k1, 0); tb1 = ldT(Bp, ldb, n0, k1, 1); }
        }
        short8 af[4], bfr[4];
#pragma unroll
        for (int f = 0; f < 4; ++f)
            af[f] = *(const short8*)&As[cur][wm + f * 16 + l16][quad * 8];
#pragma unroll
        for (int f = 0; f < 4; ++f)
            bfr[f] = *(const short8*)&Bs[cur][wn + f * 16 + l16][quad * 8];
#pragma unroll
        for (int fm = 0; fm < 4; ++fm)
#pragma unroll
            for (int fn = 0; fn < 4; ++fn)
                acc[fm][fn] = __builtin_amdgcn_mfma_f32_16x16x32_bf16(
                    af[fm], bfr[fn], acc[fm][fn], 0, 0, 0);
        if (t + 1 < NT) {
            if constexpr (AK == SK_BF16_TRANS) { wrT(ta0, 0, As[nxt]); wrT(ta1, 1, As[nxt]); }
            if constexpr (BK == SK_BF16_TRANS) { wrT(tb0, 0, Bs[nxt]); wrT(tb1, 1, Bs[nxt]); }
        }
        __syncthreads();
    }
}

// ---------------------------------------------------------------------------
// T1[n][k] (T-layout, slot 0, for power chain) AND Wf fragment-major copy for
// the scan: Wf[nb][kk][l16][quad][8], nb=n>>4 — one wave b-load = 1KB contig.
// ---------------------------------------------------------------------------
__global__ __launch_bounds__(256) void k_weff(
    const float* __restrict__ Aw, const float* __restrict__ Asc,
    unsigned short* __restrict__ T1, unsigned short* __restrict__ Wf)
{
    const int n   = blockIdx.x;
    const int tid = threadIdx.x;
    const int lane = tid & 63, wave = tid >> 6;
    float v0 = Aw[(size_t)n * NXX + tid];
    float v1 = Aw[(size_t)n * NXX + 256 + tid];
    __shared__ float sred[4];
    float m = fmaxf(v0, v1);
#pragma unroll
    for (int off = 32; off; off >>= 1) m = fmaxf(m, __shfl_down(m, off));
    if (lane == 0) sred[wave] = m;
    __syncthreads();
    if (tid == 0) sred[0] = fmaxf(fmaxf(sred[0], sred[1]), fmaxf(sred[2], sred[3]));
    __syncthreads();
    const float mm = sred[0];
    __syncthreads();
    float e0 = expf(v0 - mm), e1 = expf(v1 - mm);
    float s = e0 + e1;
#pragma unroll
    for (int off = 32; off; off >>= 1) s += __shfl_down(s, off);
    if (lane == 0) sred[wave] = s;
    __syncthreads();
    if (tid == 0) sred[0] = sred[0] + sred[1] + sred[2] + sred[3];
    __syncthreads();
    const float inv = 1.0f / sred[0];
    float sc0 = 1.0f - 0.1f * (1.0f / (1.0f + expf(-Asc[(size_t)n * NXX + tid])));
    float sc1 = 1.0f - 0.1f * (1.0f / (1.0f + expf(-Asc[(size_t)n * NXX + 256 + tid])));
    unsigned short h0 = f2bf(sc0 * e0 * inv);
    unsigned short h1 = f2bf(sc1 * e1 * inv);
    unsigned short* out = T1 + (size_t)n * NXX;
    out[tid]       = h0;
    out[tid + 256] = h1;
    // fragment-major copy: elem (n,k) -> nb*8192 + kk*512 + l16*32 + q*8 + (k&7)
    const int nb = n >> 4, l16n = n & 15;
    int k0 = tid;
    Wf[(size_t)nb * 8192 + (k0 >> 5) * 512 + l16n * 32 + ((k0 >> 3) & 3) * 8 + (k0 & 7)] = h0;
    int k1 = tid + 256;
    Wf[(size_t)nb * 8192 + (k1 >> 5) * 512 + l16n * 32 + ((k1 >> 3) & 3) * 8 + (k1 & 7)] = h1;
}

// ---------------------------------------------------------------------------
// prep: Bw -> Bf (frag-major), Ew -> Ef (frag-major), x -> G slab 0 (bf16)
// ---------------------------------------------------------------------------
__global__ __launch_bounds__(256) void k_prep(
    const float* __restrict__ Bw, const float* __restrict__ Ew,
    const float* __restrict__ x,
    unsigned short* __restrict__ Bf, unsigned short* __restrict__ Ef,
    unsigned short* __restrict__ G0)
{
    int i = (blockIdx.x * 256 + threadIdx.x) * 4;
    if (i < 65536) {           // Bw: 512 x 128, frag-major dst
        int xr = i >> 7, u0 = i & 127;
        float4 v = *(const float4*)(Bw + i);
        ushort4v h = { f2bf(v.x), f2bf(v.y), f2bf(v.z), f2bf(v.w) };
        size_t dst = (size_t)(xr >> 4) * 2048 + (u0 >> 5) * 512 +
                     (xr & 15) * 32 + ((u0 >> 3) & 3) * 8 + (u0 & 7);
        *(ushort4v*)(Bf + dst) = h;
    } else if (i < 98304) {    // Ew: 512 x 64, frag-major dst
        int k = i - 65536;
        int xr = k >> 6, u0 = k & 63;
        float4 v = *(const float4*)(Ew + k);
        ushort4v h = { f2bf(v.x), f2bf(v.y), f2bf(v.z), f2bf(v.w) };
        size_t dst = (size_t)(xr >> 4) * 1024 + (u0 >> 5) * 512 +
                     (xr & 15) * 32 + ((u0 >> 3) & 3) * 8 + (u0 & 7);
        *(ushort4v*)(Ef + dst) = h;
    } else {                   // x -> G0, linear
        int k = i - 98304;
        float4 v = *(const float4*)(x + k);
        ushort4v h = { f2bf(v.x), f2bf(v.y), f2bf(v.z), f2bf(v.w) };
        *(ushort4v*)(G0 + k) = h;
    }
}

// ---------------------------------------------------------------------------
// Batched power products in T-space: slot ds[z] = slot ns[z] (NAT) * ts[z] (TRANS)
// ---------------------------------------------------------------------------
__global__ __launch_bounds__(256) void k_mulN(unsigned short* __restrict__ powb,
                                              int4 ns, int4 ts, int4 ds)
{
    const int z = blockIdx.z;
    const int an = (z == 0) ? ns.x : (z == 1) ? ns.y : (z == 2) ? ns.z : ns.w;
    const int at = (z == 0) ? ts.x : (z == 1) ? ts.y : (z == 2) ? ts.z : ts.w;
    const int ad = (z == 0) ? ds.x : (z == 1) ? ds.y : (z == 2) ? ds.z : ds.w;
    const unsigned short* A = powb + (size_t)an * MS;
    const unsigned short* B = powb + (size_t)at * MS;
    unsigned short*       D = powb + (size_t)ad * MS;
    __shared__ unsigned short As[2][128][LDK];
    __shared__ unsigned short Bs2[2][128][LDK];
    f32x4 acc[4][4] = {};
    const int row0 = blockIdx.y * 128, n0 = blockIdx.x * 128;
    gemm2_mainloop<SK_BF16_NAT, SK_BF16_TRANS>(acc, A, NXX, B, NXX, NXX, row0, n0, As, Bs2);
    const int tid = threadIdx.x;
    const int lane = tid & 63, wave = tid >> 6;
    const int wm = (wave >> 1) * 64, wn = (wave & 1) * 64;
    const int l16 = lane & 15, quad = lane >> 4;
#pragma unroll
    for (int fm = 0; fm < 4; ++fm)
#pragma unroll
        for (int fn = 0; fn < 4; ++fn)
#pragma unroll
            for (int r = 0; r < 4; ++r) {
                int m = row0 + wm + fm * 16 + quad * 4 + r;
                int n = n0 + wn + fn * 16 + l16;
                D[(size_t)m * NXX + n] = f2bf(acc[fm][fn][r]);
            }
}

// ---------------------------------------------------------------------------
// Fused Hillis-Steele level (NC=64 slabs) + piggybacked power squaring.
// ---------------------------------------------------------------------------
__global__ __launch_bounds__(256) void k_hs_sq(
    const unsigned short* __restrict__ vsrc, unsigned short* __restrict__ vdst,
    const unsigned short* __restrict__ Am, int s,
    unsigned short* __restrict__ powb, int sqa, int sqd)
{
    const int z = blockIdx.z;
    const int tid = threadIdx.x;
    __shared__ unsigned short As[2][128][LDK];
    __shared__ unsigned short Bs2[2][128][LDK];
    const int lane = tid & 63, wave = tid >> 6;
    const int wm = (wave >> 1) * 64, wn = (wave & 1) * 64;
    const int l16 = lane & 15, quad = lane >> 4;

    if (z >= NC) {
        const unsigned short* Aq = powb + (size_t)sqa * MS;
        unsigned short*       Dq = powb + (size_t)sqd * MS;
        const int row0 = (blockIdx.y + 2 * (z - NC)) * 128;
        const int n0   = blockIdx.x * 128;
        f32x4 acc[4][4] = {};
        gemm2_mainloop<SK_BF16_NAT, SK_BF16_TRANS>(acc, Aq, NXX, Aq, NXX, NXX, row0, n0, As, Bs2);
#pragma unroll
        for (int fm = 0; fm < 4; ++fm)
#pragma unroll
            for (int fn = 0; fn < 4; ++fn)
#pragma unroll
                for (int r = 0; r < 4; ++r) {
                    int m = row0 + wm + fm * 16 + quad * 4 + r;
                    int n = n0 + wn + fn * 16 + l16;
                    Dq[(size_t)m * NXX + n] = f2bf(acc[fm][fn][r]);
                }
        return;
    }

    const int c = z;
    const int row0 = blockIdx.y * 128, n0 = blockIdx.x * 128;
    if (c < s) {
        const unsigned short* sp = vsrc + (size_t)c * BS;
        unsigned short*       dp = vdst + (size_t)c * BS;
#pragma unroll
        for (int i = 0; i < 8; ++i) {
            int idx = tid + i * 256;
            int r = idx >> 4, cc = (idx & 15) << 3;
            *(ushort8*)(dp + (size_t)(row0 + r) * NXX + n0 + cc) =
                *(const ushort8*)(sp + (size_t)(row0 + r) * NXX + n0 + cc);
        }
        return;
    }
    f32x4 acc[4][4] = {};
    gemm2_mainloop<SK_BF16_NAT, SK_BF16_NAT>(acc, vsrc + (size_t)(c - s) * BS, NXX,
                                             Am, NXX, NXX, row0, n0, As, Bs2);
    const unsigned short* Cp = vsrc + (size_t)c * BS;
    unsigned short*       Dp = vdst + (size_t)c * BS;
#pragma unroll
    for (int fm = 0; fm < 4; ++fm)
#pragma unroll
        for (int fn = 0; fn < 4; ++fn)
#pragma unroll
            for (int r = 0; r < 4; ++r) {
                int m = row0 + wm + fm * 16 + quad * 4 + r;
                int n = n0 + wn + fn * 16 + l16;
                float v = acc[fm][fn][r] + bf2f(Cp[(size_t)m * NXX + n]);
                Dp[(size_t)m * NXX + n] = f2bf(v);
            }
}

// ---------------------------------------------------------------------------
// Seed-correction GEMM:  t = blockIdx.z, c = t/4, j = t%4:
//   X[t] += seed[c] @ W^{j+1};  Y = X[:,:,511]
// ---------------------------------------------------------------------------
__global__ __launch_bounds__(256) void k_xcorr(
    const unsigned short* __restrict__ seeds, const unsigned short* __restrict__ powb,
    float* __restrict__ X, float* __restrict__ Y)
{
    const int t = blockIdx.z;
    const int c = t >> 2, j = t & 3;
    const int row0 = blockIdx.y * 128, n0 = blockIdx.x * 128;
    __shared__ unsigned short As[2][128][LDK];
    __shared__ unsigned short Bs2[2][128][LDK];
    f32x4 acc[4][4] = {};
    gemm2_mainloop<SK_BF16_NAT, SK_BF16_NAT>(acc, seeds + (size_t)c * BS, NXX,
                                             powb + (size_t)j * MS, NXX, NXX,
                                             row0, n0, As, Bs2);
    const int tid = threadIdx.x;
    const int lane = tid & 63, wave = tid >> 6;
    const int wm = (wave >> 1) * 64, wn = (wave & 1) * 64;
    const int l16 = lane & 15, quad = lane >> 4;
    float* Xt = X + (size_t)t * BB * NXX;
#pragma unroll
    for (int fm = 0; fm < 4; ++fm)
#pragma unroll
        for (int fn = 0; fn < 4; ++fn)
#pragma unroll
            for (int r = 0; r < 4; ++r) {
                int m = row0 + wm + fm * 16 + quad * 4 + r;
                int n = n0 + wn + fn * 16 + l16;
                float v = acc[fm][fn][r] + Xt[(size_t)m * NXX + n];
                Xt[(size_t)m * NXX + n] = v;
                if (n == NXX - 1) Y[(size_t)t * BB + m] = v;
            }
}

// ---------------------------------------------------------------------------
// Pass A: fused per-chunk zero-init recurrence. All b-operands (Wf/Bf/Ef) are
// stored FRAGMENT-MAJOR so each wave b-load is one contiguous 1KB read —
// removes the 16-cacheline-per-instruction TA scatter that capped the CU at
// ~24us per block-step (rounds 2-7 invariant).
// ---------------------------------------------------------------------------
__global__ __launch_bounds__(1024, 8) void k_scanA(
    const float* __restrict__ U, const float* __restrict__ Dm,
    const unsigned short* __restrict__ Bf, const unsigned short* __restrict__ Ef,
    const unsigned short* __restrict__ Wf,
    unsigned short* __restrict__ Gout,
    float* __restrict__ X)
{
    const int c   = blockIdx.x;          // chunk 0..63
    const int r0  = blockIdx.y * 32;     // batch-row base
    const int tid = threadIdx.x;         // 0..1023
    const int lane = tid & 63, wave = tid >> 6;   // wave 0..15
    const int l16 = lane & 15, quad = lane >> 4;

    __shared__ unsigned short Sb[32][520];   // state bf16
    __shared__ unsigned short Ub[32][136];   // U tile bf16
    __shared__ unsigned short Db[32][72];    // D tile bf16

    // fragment-major per-lane offsets: nb = wave*2+g; lane-linear inner 1KB
    int woff[2], bwoff[2], ewoff[2];
#pragma unroll
    for (int g = 0; g < 2; ++g) {
        int nb = wave * 2 + g;
        int ln = l16 * 32 + quad * 8;
        woff[g]  = nb * 8192 + ln;   // Wf: 16 kk-slices of 512
        bwoff[g] = nb * 2048 + ln;   // Bf: 4 kk-slices
        ewoff[g] = nb * 1024 + ln;   // Ef: 2 kk-slices
    }

    f32x4 acc[2][2];

    for (int j = 0; j < CL; ++j) {
        const int t = c * CL + j;
        // ---- stage U (32x128) and D (32x64) f32 -> bf16 into LDS ----
        {
            int row = tid >> 5;               // 0..31
            int uc  = (tid & 31) * 4;         // 4 floats -> 128 cols
            const float* up = U + ((size_t)t * BB + r0 + row) * NUU + uc;
            float4 a0 = *(const float4*)(up);
            ushort4v h0 = { f2bf(a0.x), f2bf(a0.y), f2bf(a0.z), f2bf(a0.w) };
            *(ushort4v*)&Ub[row][uc] = h0;
            int dc = (tid & 31) * 2;          // 2 floats -> 64 cols
            const float* dp = Dm + ((size_t)t * BB + r0 + row) * NDD + dc;
            float2 b0 = *(const float2*)(dp);
            unsigned pk = (unsigned)f2bf(b0.x) | ((unsigned)f2bf(b0.y) << 16);
            *(unsigned*)&Db[row][dc] = pk;
        }
        __syncthreads();   // staging (and prev-step Sb writes) visible

#pragma unroll
        for (int f = 0; f < 2; ++f)
#pragma unroll
            for (int g = 0; g < 2; ++g) acc[f][g] = (f32x4){0.f, 0.f, 0.f, 0.f};

        // ---- inj: U @ Bw^T  (K=128) ----
#pragma unroll
        for (int kk = 0; kk < 4; ++kk) {
            short8 a0 = *(const short8*)&Ub[l16][kk * 32 + quad * 8];
            short8 a1 = *(const short8*)&Ub[16 + l16][kk * 32 + quad * 8];
#pragma unroll
            for (int g = 0; g < 2; ++g) {
                short8 b = *(const short8*)(Bf + bwoff[g] + kk * 512);
                acc[0][g] = __builtin_amdgcn_mfma_f32_16x16x32_bf16(a0, b, acc[0][g], 0, 0, 0);
                acc[1][g] = __builtin_amdgcn_mfma_f32_16x16x32_bf16(a1, b, acc[1][g], 0, 0, 0);
            }
        }
        // ---- inj: D @ Ew^T  (K=64) ----
#pragma unroll
        for (int kk = 0; kk < 2; ++kk) {
            short8 a0 = *(const short8*)&Db[l16][kk * 32 + quad * 8];
            short8 a1 = *(const short8*)&Db[16 + l16][kk * 32 + quad * 8];
#pragma unroll
            for (int g = 0; g < 2; ++g) {
                short8 b = *(const short8*)(Ef + ewoff[g] + kk * 512);
                acc[0][g] = __builtin_amdgcn_mfma_f32_16x16x32_bf16(a0, b, acc[0][g], 0, 0, 0);
                acc[1][g] = __builtin_amdgcn_mfma_f32_16x16x32_bf16(a1, b, acc[1][g], 0, 0, 0);
            }
        }
        // ---- state @ W  (K=512) ----
        if (j > 0) {
#pragma unroll
            for (int kk = 0; kk < 16; ++kk) {
                short8 a0 = *(const short8*)&Sb[l16][kk * 32 + quad * 8];
                short8 a1 = *(const short8*)&Sb[16 + l16][kk * 32 + quad * 8];
#pragma unroll
                for (int g = 0; g < 2; ++g) {
                    short8 b = *(const short8*)(Wf + woff[g] + kk * 512);
                    acc[0][g] = __builtin_amdgcn_mfma_f32_16x16x32_bf16(a0, b, acc[0][g], 0, 0, 0);
                    acc[1][g] = __builtin_amdgcn_mfma_f32_16x16x32_bf16(a1, b, acc[1][g], 0, 0, 0);
                }
            }
        }
        __syncthreads();   // all reads of Sb done before overwrite

        // ---- write new state + xA (f32) ----
#pragma unroll
        for (int f = 0; f < 2; ++f)
#pragma unroll
            for (int g = 0; g < 2; ++g) {
                int n = wave * 32 + g * 16 + l16;
#pragma unroll
                for (int rr = 0; rr < 4; ++rr) {
                    int mr = f * 16 + quad * 4 + rr;
                    float v = acc[f][g][rr];
                    unsigned short hb = f2bf(v);
                    Sb[mr][n] = hb;
                    X[((size_t)t * BB + r0 + mr) * NXX + n] = v;
                    if (j == CL - 1)
                        Gout[((size_t)(c + 1) * BB + r0 + mr) * NXX + n] = hb;
                }
            }
    }
}

// ---------------------------------------------------------------------------
extern "C" void kernel_launch(void* const* d_in, const int* in_sizes, int n_in,
                              void* d_out, int out_size, void* d_ws, size_t ws_size,
                              hipStream_t stream)
{
    const float* x   = (const float*)d_in[0];
    const float* U   = (const float*)d_in[1];
    const float* Dm  = (const float*)d_in[2];
    const float* Aw  = (const float*)d_in[3];
    const float* Asc = (const float*)d_in[4];
    const float* Bw  = (const float*)d_in[5];
    const float* Ew  = (const float*)d_in[6];

    float* Xout = (float*)d_out;
    float* Yout = Xout + (size_t)TT * BB * NXX;

    // ws layout (bf16): power slots 0..8 (T-layout W^{1..4}, W^{8..128});
    // Wf (frag-major W, 1 MS); Bf 512x128; Ef 512x64; G 65 slabs; vA 64 slabs
    unsigned short* powb = (unsigned short*)d_ws;
    unsigned short* Wf   = powb + (size_t)9 * MS;
    unsigned short* Bf   = Wf + (size_t)MS;
    unsigned short* Ef   = Bf + (size_t)NXX * NUU;
    unsigned short* Gbuf = Ef + (size_t)NXX * NDD;
    unsigned short* vA   = Gbuf + (size_t)(NC + 1) * BS;

    dim3 blk(256);
    dim3 blkScan(1024);

    k_weff<<<dim3(512), blk, 0, stream>>>(Aw, Asc, powb, Wf);
    k_prep<<<dim3(224), blk, 0, stream>>>(Bw, Ew, x, Bf, Ef, Gbuf);

    // power products: slots 0..3 = W^1..W^4 (xcorr + HS level 1);
    // W^{8..128} ride along inside the HS launches below.
    k_mulN<<<dim3(4, 4, 1), blk, 0, stream>>>(powb,
        make_int4(0, 0, 0, 0), make_int4(0, 0, 0, 0), make_int4(1, 0, 0, 0));
    k_mulN<<<dim3(4, 4, 2), blk, 0, stream>>>(powb,
        make_int4(1, 1, 0, 0), make_int4(0, 1, 0, 0), make_int4(2, 3, 0, 0));

    // Pass A: zero-init chunk scans (4 steps, 512 blocks = 2/CU)
    k_scanA<<<dim3(NC, 8), blkScan, 0, stream>>>(
        U, Dm, Bf, Ef, Wf, Gbuf, Xout);

    // Hillis-Steele prefix over 64 chunk-start slabs, ping-pong G <-> vA,
    // with piggybacked squarings W^8..W^128.  Final seeds land in G.
    k_hs_sq<<<dim3(4, 2, NC + 2), blk, 0, stream>>>(Gbuf, vA, powb + (size_t)3 * MS, 1,
                                                    powb, 3, 4);
    k_hs_sq<<<dim3(4, 2, NC + 2), blk, 0, stream>>>(vA, Gbuf, powb + (size_t)4 * MS, 2,
                                                    powb, 4, 5);
    k_hs_sq<<<dim3(4, 2, NC + 2), blk, 0, stream>>>(Gbuf, vA, powb + (size_t)5 * MS, 4,
                                                    powb, 5, 6);
    k_hs_sq<<<dim3(4, 2, NC + 2), blk, 0, stream>>>(vA, Gbuf, powb + (size_t)6 * MS, 8,
                                                    powb, 6, 7);
    k_hs_sq<<<dim3(4, 2, NC + 2), blk, 0, stream>>>(Gbuf, vA, powb + (size_t)7 * MS, 16,
                                                    powb, 7, 8);
    k_hs_sq<<<dim3(4, 2, NC), blk, 0, stream>>>(vA, Gbuf, powb + (size_t)8 * MS, 32,
                                                powb, 0, 0);

    // Seed-correction GEMM: X[t] += seed[t/4] @ W^{(t%4)+1}; writes Y
    k_xcorr<<<dim3(4, 2, TT), blk, 0, stream>>>(Gbuf, powb, Xout, Yout);
}